// Round 1
// 291.728 us; speedup vs baseline: 1.0619x; 1.0619x over previous
//
#include <hip/hip_runtime.h>

#define CC 384
#define HW 3136            // 56*56
#define WIDTH 56
#define PLANE_ELEMS (CC*HW)  // 1204224
#define EPS 1e-5f

// bf16 x_pw for plane p lives in the 2nd half of plane p's f32 output slot:
// ushort index = p*6272 + 3136 + j   (slot = 12544 B = 6272 ushorts)
#define SLOT_U 6272
#define HALF_U 3136

// Pre-packed W (bf16) in workspace: [12 kt][384 o][40 kk]
// kk<32 = bf16(W[o][kt*32+kk]); kk 32..39 = zero pad so the row stride is
// 80 B: 16B-aligned rows for ds_read_b128, bank stride 20 -> 2-way (free).
#define WROW 40
#define WSTEP_U (CC*WROW)        // 15360 ushorts per k-step = 30720 B
#define WP_TOTAL (12*WSTEP_U)    // 184320 ushorts = 368640 B of d_ws

typedef __attribute__((ext_vector_type(8))) short bf16x8;
typedef __attribute__((ext_vector_type(4))) float f32x4;

static __device__ __forceinline__ float bf2f(unsigned short u) {
  union { unsigned int i; float f; } x; x.i = ((unsigned int)u) << 16; return x.f;
}
static __device__ __forceinline__ unsigned short f2bf(float f) {
  union { float f; unsigned int i; } x; x.f = f;
  unsigned int r = x.i + 0x7fffu + ((x.i >> 16) & 1u);
  return (unsigned short)(r >> 16);
}

// ---------------------------------------------------------------------------
// Kernel 0: pre-pack W f32 -> bf16 in k-step-major padded layout (runs once
// per launch; 184320 elements, ~2 us). Same f2bf rounding as before.
// ---------------------------------------------------------------------------
__global__ __launch_bounds__(256) void pack_w(
    const float* __restrict__ wmat, unsigned short* __restrict__ wp)
{
  int i = blockIdx.x * 256 + threadIdx.x;      // grid sized exactly
  int kt  = i / WSTEP_U;
  int rem = i - kt * WSTEP_U;
  int o   = rem / WROW;
  int kk  = rem - o * WROW;
  unsigned short v = 0;
  if (kk < 32) v = f2bf(wmat[o * CC + kt * 32 + kk]);
  wp[i] = v;
}

// ---------------------------------------------------------------------------
// Kernel A v2: one block = 64 spatial x ALL 384 out-channels.
//  - x staged from HBM exactly once (no 6x o-tile re-read -> FETCH ~77MB)
//  - W staged per k-step from pre-packed bf16 via global_load_lds (no LDS
//    write instrs, no conflicts, L2-resident)
//  - X transpose staging: thread = (j, k-octet): 8 coalesced dword loads,
//    one conflict-free ds_write_b128 (replaces 8x 8-way ds_write_u16)
//  - wave w owns o-range [w*96, w*96+96): 4 j-frags x 6 o-frags = 24 MFMA
//    per k-step against 10 ds_read_b128.
// ---------------------------------------------------------------------------
__global__ __launch_bounds__(256, 3) void pw_gemm_bn_res(
    const float* __restrict__ xin,
    const unsigned short* __restrict__ wp,
    const float* __restrict__ pwg, const float* __restrict__ pwb,
    const float* __restrict__ pwm, const float* __restrict__ pwv,
    unsigned short* __restrict__ xpw)   // = (ushort*)d_out
{
  __shared__ __align__(16) unsigned short Xt[64 * 40];   //  5120 B, [j][k] pad 40
  __shared__ __align__(16) unsigned short Wt[WSTEP_U];   // 30720 B, [o][k] pad 40
  __shared__ float scaleS[CC];
  __shared__ float shiftS[CC];

  const int tid = threadIdx.x;
  const int j0 = blockIdx.x * 64;   // spatial tile (3136 = 49*64)
  const int b  = blockIdx.y;
  const size_t bbase = (size_t)b * PLANE_ELEMS;

  for (int o = tid; o < CC; o += 256) {
    float s = pwg[o] * rsqrtf(pwv[o] + EPS);
    scaleS[o] = s;
    shiftS[o] = pwb[o] - pwm[o] * s;
  }

  const int lane = tid & 63;
  const int wid  = tid >> 6;        // wave id: o-range owner / k-octet / W-chunk set
  const int l15  = lane & 15;
  const int q    = lane >> 4;

  f32x4 acc[4][6] = {};             // static-indexed only (stays in VGPRs)

  // X staging role: this thread loads 8 consecutive k for spatial j0+lane
  const float* xsrc0 = xin + bbase + (size_t)(wid * 8) * HW + (j0 + lane);

  for (int kt = 0; kt < 12; ++kt) {
    const int c0 = kt * 32;
    __syncthreads();
    // ---- X tile: 64j x 32k, transposed to [j][k] bf16 ----
    {
      const float* src = xsrc0 + (size_t)c0 * HW;
      float v0 = src[0 * HW], v1 = src[1 * HW], v2 = src[2 * HW], v3 = src[3 * HW];
      float v4 = src[4 * HW], v5 = src[5 * HW], v6 = src[6 * HW], v7 = src[7 * HW];
      bf16x8 u;
      u[0] = (short)f2bf(v0); u[1] = (short)f2bf(v1);
      u[2] = (short)f2bf(v2); u[3] = (short)f2bf(v3);
      u[4] = (short)f2bf(v4); u[5] = (short)f2bf(v5);
      u[6] = (short)f2bf(v6); u[7] = (short)f2bf(v7);
      *((bf16x8*)&Xt[lane * 40 + wid * 8]) = u;   // 16B aligned, banks balanced
    }
    // ---- W tile: 384o x 32k (+pad) = 30 chunks of 1KB via global_load_lds ----
    {
      const unsigned short* g = wp + (size_t)kt * WSTEP_U;
      #pragma unroll
      for (int i = 0; i < 8; ++i) {
        int c = i * 4 + wid;                     // waves 0,1: 8 chunks; 2,3: 7
        if (c < 30) {
          __builtin_amdgcn_global_load_lds(
              (const __attribute__((address_space(1))) unsigned int*)(g + c * 512 + lane * 8),
              (__attribute__((address_space(3))) unsigned int*)(&Wt[c * 512]),
              16, 0, 0);
        }
      }
    }
    __syncthreads();

    bf16x8 a[4];
    #pragma unroll
    for (int jf = 0; jf < 4; ++jf)
      a[jf] = *((const bf16x8*)&Xt[(jf * 16 + l15) * 40 + q * 8]);

    #pragma unroll
    for (int of = 0; of < 6; ++of) {
      bf16x8 bb = *((const bf16x8*)&Wt[(wid * 96 + of * 16 + l15) * WROW + q * 8]);
      #pragma unroll
      for (int jf = 0; jf < 4; ++jf)
        acc[jf][of] = __builtin_amdgcn_mfma_f32_16x16x32_bf16(a[jf], bb, acc[jf][of], 0, 0, 0);
    }
  }

  // ---- epilogue: BN + residual, write bf16 stash ----
  // D layout: col = l15 -> o within 16-frag, row = q*4+r -> j within 16-frag
  const int ob = wid * 96;
  #pragma unroll
  for (int of = 0; of < 6; ++of) {
    const int o = ob + of * 16 + l15;
    const float s = scaleS[o], t = shiftS[o];
    #pragma unroll
    for (int jf = 0; jf < 4; ++jf) {
      const int j = j0 + jf * 16 + q * 4;
      f32x4 av = acc[jf][of];
      float4 xr = *((const float4*)(xin + bbase + (size_t)o * HW + j));
      ushort4 w4;
      w4.x = f2bf(av[0] * s + t + xr.x);
      w4.y = f2bf(av[1] * s + t + xr.y);
      w4.z = f2bf(av[2] * s + t + xr.z);
      w4.w = f2bf(av[3] * s + t + xr.w);
      size_t pidx = (size_t)(b * CC + o) * SLOT_U + HALF_U + j;
      *((ushort4*)(xpw + pidx)) = w4;
    }
  }
}

// ---------------------------------------------------------------------------
// Kernel B (MFMA Toeplitz): 13x13 depthwise conv + BN_k + center-tap branch
// + exact GELU, one block per (b,c) plane. (unchanged this round)
// ---------------------------------------------------------------------------
#define TSTRIDE 88
#define TROWS 76

__global__ __launch_bounds__(256) void dw_conv_mfma(
    float* __restrict__ outf,                 // d_out as f32
    const unsigned short* __restrict__ stash, // d_out as ushort (bf16 halves)
    const float* __restrict__ dwkw,
    const float* __restrict__ dkg, const float* __restrict__ dkb,
    const float* __restrict__ dkm, const float* __restrict__ dkv,
    const float* __restrict__ d1w,
    const float* __restrict__ d1g, const float* __restrict__ d1b,
    const float* __restrict__ d1m, const float* __restrict__ d1v)
{
  __shared__ __align__(16) unsigned short tile[TROWS * TSTRIDE]; // 13376 B
  __shared__ __align__(16) unsigned short Bt[13 * 16 * 32];      // 13312 B

  const int bc = blockIdx.x;
  const int c = bc % CC;
  const size_t plane_u = (size_t)bc * SLOT_U + HALF_U;  // bf16 stash base
  const size_t plane_f = (size_t)bc * HW;               // f32 out base
  const int tid = threadIdx.x;

  // stage plane into zero-padded bf16 tile (halo 6; extra rows/cols zeroed)
  for (int i = tid; i < TROWS * TSTRIDE; i += 256) {
    int r = i / TSTRIDE, col = i - r * TSTRIDE;
    int gy = r - 6, gx = col - 6;
    unsigned short v = 0;
    if ((unsigned)gy < (unsigned)WIDTH && (unsigned)gx < (unsigned)WIDTH)
      v = stash[plane_u + gy * WIDTH + gx];
    tile[i] = v;
  }
  // build Toeplitz B: Bt[ky][n][k] = w[ky][k-n] (0 if k-n outside [0,13))
  for (int i = tid; i < 13 * 512; i += 256) {
    int ky = i >> 9, rem = i & 511, n = rem >> 5, k = rem & 31;
    int kx = k - n;
    float wv = ((unsigned)kx < 13u) ? dwkw[c * 169 + ky * 13 + kx] : 0.f;
    Bt[i] = f2bf(wv);
  }

  const float sk = dkg[c] * rsqrtf(dkv[c] + EPS);
  const float tk = dkb[c] - dkm[c] * sk;
  const float s1 = d1g[c] * rsqrtf(d1v[c] + EPS);
  const float a1 = d1w[c] * s1;
  const float t1 = d1b[c] - d1m[c] * s1;
  const float tsum = tk + t1;

  __syncthreads();

  const int lane = tid & 63;
  const int l15  = lane & 15;   // A: m index / D: col (x offset)
  const int q    = lane >> 4;   // A/B: k quad / D: row group
  const int wid  = tid >> 6;

  // hoist B fragments (channel-constant) into registers
  bf16x8 bfr[13];
  #pragma unroll
  for (int ky = 0; ky < 13; ++ky)
    bfr[ky] = *((const bf16x8*)&Bt[(ky * 16 + l15) * 32 + q * 8]);

  // 16 output tiles of 16x16 cover 64x64 >= 56x56; 4 waves -> 4 tiles each
  for (int t = wid; t < 16; t += 4) {
    const int y0 = (t >> 2) * 16, x0 = (t & 3) * 16;
    f32x4 acc = {0.f, 0.f, 0.f, 0.f};
    #pragma unroll
    for (int ky = 0; ky < 13; ++ky) {
      bf16x8 a = *((const bf16x8*)&tile[(y0 + l15 + ky) * TSTRIDE + x0 + q * 8]);
      acc = __builtin_amdgcn_mfma_f32_16x16x32_bf16(a, bfr[ky], acc, 0, 0, 0);
    }
    // epilogue: D row m = q*4+r, col n = l15
    const int x = x0 + l15;
    if (x < WIDTH) {
      #pragma unroll
      for (int r = 0; r < 4; ++r) {
        const int y = y0 + q * 4 + r;
        if (y < WIDTH) {
          float ctr = bf2f(tile[(y + 6) * TSTRIDE + x + 6]);
          float v = acc[r] * sk + tsum + ctr * a1;
          outf[plane_f + y * WIDTH + x] =
              0.5f * v * (1.f + erff(v * 0.70710678118654752f));
        }
      }
    }
  }
}

extern "C" void kernel_launch(void* const* d_in, const int* in_sizes, int n_in,
                              void* d_out, int out_size, void* d_ws, size_t ws_size,
                              hipStream_t stream) {
  const float* x     = (const float*)d_in[0];
  const float* pw_w  = (const float*)d_in[1];
  const float* pw_g  = (const float*)d_in[2];
  const float* pw_b  = (const float*)d_in[3];
  const float* pw_m  = (const float*)d_in[4];
  const float* pw_v  = (const float*)d_in[5];
  const float* dwk_w = (const float*)d_in[6];
  const float* dwk_g = (const float*)d_in[7];
  const float* dwk_b = (const float*)d_in[8];
  const float* dwk_m = (const float*)d_in[9];
  const float* dwk_v = (const float*)d_in[10];
  const float* dw1_w = (const float*)d_in[11];
  const float* dw1_g = (const float*)d_in[12];
  const float* dw1_b = (const float*)d_in[13];
  const float* dw1_m = (const float*)d_in[14];
  const float* dw1_v = (const float*)d_in[15];
  float* outf = (float*)d_out;
  unsigned short* outu = (unsigned short*)d_out;
  unsigned short* wpack = (unsigned short*)d_ws;   // needs 368640 B

  pack_w<<<WP_TOTAL / 256, 256, 0, stream>>>(pw_w, wpack);

  dim3 gridA(HW / 64, 16);
  pw_gemm_bn_res<<<gridA, 256, 0, stream>>>(x, wpack, pw_g, pw_b, pw_m, pw_v, outu);

  dim3 gridB(16 * CC);
  dw_conv_mfma<<<gridB, 256, 0, stream>>>(outf, outu, dwk_w,
      dwk_g, dwk_b, dwk_m, dwk_v, dw1_w, dw1_g, dw1_b, dw1_m, dw1_v);
}

// Round 2
// 255.389 us; speedup vs baseline: 1.2130x; 1.1423x over previous
//
#include <hip/hip_runtime.h>

#define CC 384
#define HW 3136            // 56*56
#define WIDTH 56
#define PLANE_ELEMS (CC*HW)  // 1204224
#define EPS 1e-5f

// bf16 x_pw for plane p lives in the 2nd half of plane p's f32 output slot:
// ushort index = p*6272 + 3136 + j   (slot = 12544 B = 6272 ushorts)
#define SLOT_U 6272
#define HALF_U 3136

// Pre-packed W (bf16) in workspace: [12 kt][384 o][40 kk]
#define WROW 40
#define WSTEP_U (CC*WROW)        // 15360 ushorts per k-step = 30720 B
#define WP_TOTAL (12*WSTEP_U)    // 184320 ushorts = 368640 B of d_ws

// Pre-packed Toeplitz B per channel: [c][13 ky][16 n][32 k] bf16
// = 6656 ushorts = 13312 B per channel = exactly 13 x 1024B wave-chunks.
#define BT_U 6656
#define BT_TOTAL (CC*BT_U)       // 2555904 ushorts = 5111808 B

typedef __attribute__((ext_vector_type(8))) short bf16x8;
typedef __attribute__((ext_vector_type(4))) float f32x4;

static __device__ __forceinline__ float bf2f(unsigned short u) {
  union { unsigned int i; float f; } x; x.i = ((unsigned int)u) << 16; return x.f;
}
static __device__ __forceinline__ unsigned short f2bf(float f) {
  union { float f; unsigned int i; } x; x.f = f;
  unsigned int r = x.i + 0x7fffu + ((x.i >> 16) & 1u);
  return (unsigned short)(r >> 16);
}

// ---------------------------------------------------------------------------
// Kernel 0: pre-pack W f32 -> bf16 in k-step-major padded layout.
// ---------------------------------------------------------------------------
__global__ __launch_bounds__(256) void pack_w(
    const float* __restrict__ wmat, unsigned short* __restrict__ wp)
{
  int i = blockIdx.x * 256 + threadIdx.x;      // grid sized exactly
  int kt  = i / WSTEP_U;
  int rem = i - kt * WSTEP_U;
  int o   = rem / WROW;
  int kk  = rem - o * WROW;
  unsigned short v = 0;
  if (kk < 32) v = f2bf(wmat[o * CC + kt * 32 + kk]);
  wp[i] = v;
}

// ---------------------------------------------------------------------------
// Kernel 0b: pre-pack Toeplitz Bt per channel (bf16), built ONCE per channel
// instead of once per (b,c) block.  Bt[c][ky][n][k] = w[c][ky][k-n-2]
// (shift -2 matches the left-pad-8 tile layout in dw_conv_mfma).
// ---------------------------------------------------------------------------
__global__ __launch_bounds__(256) void pack_bt(
    const float* __restrict__ dwkw, unsigned short* __restrict__ btg)
{
  const int c = blockIdx.x;
  for (int i = threadIdx.x; i < BT_U; i += 256) {
    int ky = i >> 9, rem = i & 511, n = rem >> 5, k = rem & 31;
    int kx = k - n - 2;
    unsigned short v = 0;
    if ((unsigned)kx < 13u) v = f2bf(dwkw[c * 169 + ky * 13 + kx]);
    btg[(size_t)c * BT_U + i] = v;
  }
}

// ---------------------------------------------------------------------------
// Kernel A v2: one block = 64 spatial x ALL 384 out-channels. (unchanged)
// ---------------------------------------------------------------------------
__global__ __launch_bounds__(256, 3) void pw_gemm_bn_res(
    const float* __restrict__ xin,
    const unsigned short* __restrict__ wp,
    const float* __restrict__ pwg, const float* __restrict__ pwb,
    const float* __restrict__ pwm, const float* __restrict__ pwv,
    unsigned short* __restrict__ xpw)   // = (ushort*)d_out
{
  __shared__ __align__(16) unsigned short Xt[64 * 40];   //  5120 B, [j][k] pad 40
  __shared__ __align__(16) unsigned short Wt[WSTEP_U];   // 30720 B, [o][k] pad 40
  __shared__ float scaleS[CC];
  __shared__ float shiftS[CC];

  const int tid = threadIdx.x;
  const int j0 = blockIdx.x * 64;   // spatial tile (3136 = 49*64)
  const int b  = blockIdx.y;
  const size_t bbase = (size_t)b * PLANE_ELEMS;

  for (int o = tid; o < CC; o += 256) {
    float s = pwg[o] * rsqrtf(pwv[o] + EPS);
    scaleS[o] = s;
    shiftS[o] = pwb[o] - pwm[o] * s;
  }

  const int lane = tid & 63;
  const int wid  = tid >> 6;
  const int l15  = lane & 15;
  const int q    = lane >> 4;

  f32x4 acc[4][6] = {};             // static-indexed only (stays in VGPRs)

  const float* xsrc0 = xin + bbase + (size_t)(wid * 8) * HW + (j0 + lane);

  for (int kt = 0; kt < 12; ++kt) {
    const int c0 = kt * 32;
    __syncthreads();
    // ---- X tile: 64j x 32k, transposed to [j][k] bf16 ----
    {
      const float* src = xsrc0 + (size_t)c0 * HW;
      float v0 = src[0 * HW], v1 = src[1 * HW], v2 = src[2 * HW], v3 = src[3 * HW];
      float v4 = src[4 * HW], v5 = src[5 * HW], v6 = src[6 * HW], v7 = src[7 * HW];
      bf16x8 u;
      u[0] = (short)f2bf(v0); u[1] = (short)f2bf(v1);
      u[2] = (short)f2bf(v2); u[3] = (short)f2bf(v3);
      u[4] = (short)f2bf(v4); u[5] = (short)f2bf(v5);
      u[6] = (short)f2bf(v6); u[7] = (short)f2bf(v7);
      *((bf16x8*)&Xt[lane * 40 + wid * 8]) = u;
    }
    // ---- W tile: 384o x 32k (+pad) = 30 chunks of 1KB via global_load_lds ----
    {
      const unsigned short* g = wp + (size_t)kt * WSTEP_U;
      #pragma unroll
      for (int i = 0; i < 8; ++i) {
        int c = i * 4 + wid;
        if (c < 30) {
          __builtin_amdgcn_global_load_lds(
              (const __attribute__((address_space(1))) unsigned int*)(g + c * 512 + lane * 8),
              (__attribute__((address_space(3))) unsigned int*)(&Wt[c * 512]),
              16, 0, 0);
        }
      }
    }
    __syncthreads();

    bf16x8 a[4];
    #pragma unroll
    for (int jf = 0; jf < 4; ++jf)
      a[jf] = *((const bf16x8*)&Xt[(jf * 16 + l15) * 40 + q * 8]);

    #pragma unroll
    for (int of = 0; of < 6; ++of) {
      bf16x8 bb = *((const bf16x8*)&Wt[(wid * 96 + of * 16 + l15) * WROW + q * 8]);
      #pragma unroll
      for (int jf = 0; jf < 4; ++jf)
        acc[jf][of] = __builtin_amdgcn_mfma_f32_16x16x32_bf16(a[jf], bb, acc[jf][of], 0, 0, 0);
    }
  }

  const int ob = wid * 96;
  #pragma unroll
  for (int of = 0; of < 6; ++of) {
    const int o = ob + of * 16 + l15;
    const float s = scaleS[o], t = shiftS[o];
    #pragma unroll
    for (int jf = 0; jf < 4; ++jf) {
      const int j = j0 + jf * 16 + q * 4;
      f32x4 av = acc[jf][of];
      float4 xr = *((const float4*)(xin + bbase + (size_t)o * HW + j));
      ushort4 w4;
      w4.x = f2bf(av[0] * s + t + xr.x);
      w4.y = f2bf(av[1] * s + t + xr.y);
      w4.z = f2bf(av[2] * s + t + xr.z);
      w4.w = f2bf(av[3] * s + t + xr.w);
      size_t pidx = (size_t)(b * CC + o) * SLOT_U + HALF_U + j;
      *((ushort4*)(xpw + pidx)) = w4;
    }
  }
}

// ---------------------------------------------------------------------------
// Kernel B v2 (MFMA Toeplitz): 13x13 depthwise conv + BN_k + center-tap
// branch + exact GELU, one block per (b,c) plane.
// Changes this round (VALU-bound per rocprof: VALUBusy 68%, MfmaUtil 8.5%):
//  - tile staging fully vectorized: left halo = 8 cols (so global rows are
//    16B-aligned in LDS) -> 76 rows x 11 b128 chunks, one ds_write_b128
//    each (zero or coalesced 16B global load). ~3.3 iters/thread vs 26
//    scalar iters with div-by-88 address math.
//  - Toeplitz Bt pre-packed per channel (pack_bt) and staged with 13x
//    global_load_lds dwordx4 (13312 B exactly); per-block build retained as
//    fallback when workspace is too small.
//  - Toeplitz shift adjusted to w[k-n-2] to match the left-pad-8 layout;
//    center tap now tile[(y+6)][x+8]. Numerics identical.
// ---------------------------------------------------------------------------
#define TSTRIDE 88
#define TROWS 76
#define NCH 11   // b128 chunks per tile row (88 u16 = 11 * 8)

__global__ __launch_bounds__(256) void dw_conv_mfma(
    float* __restrict__ outf,                 // d_out as f32
    const unsigned short* __restrict__ stash, // d_out as ushort (bf16 halves)
    const unsigned short* __restrict__ btg,   // pre-packed Bt (or nullptr)
    const float* __restrict__ dwkw,
    const float* __restrict__ dkg, const float* __restrict__ dkb,
    const float* __restrict__ dkm, const float* __restrict__ dkv,
    const float* __restrict__ d1w,
    const float* __restrict__ d1g, const float* __restrict__ d1b,
    const float* __restrict__ d1m, const float* __restrict__ d1v)
{
  __shared__ __align__(16) unsigned short tile[TROWS * TSTRIDE]; // 13376 B
  __shared__ __align__(16) unsigned short Bt[13 * 16 * 32];      // 13312 B

  const int bc = blockIdx.x;
  const int c = bc % CC;
  const size_t plane_u = (size_t)bc * SLOT_U + HALF_U;  // bf16 stash base
  const size_t plane_f = (size_t)bc * HW;               // f32 out base
  const int tid = threadIdx.x;
  const int lane = tid & 63;
  const int wid  = tid >> 6;

  // ---- stage plane into zero-padded bf16 tile: all-vector b128 writes ----
  // tile[r][col]: col 0..7 zero | col 8..63 = row gy=r-6 | col 64..87 zero
  for (int i = tid; i < TROWS * NCH; i += 256) {
    int r = i / NCH, ch = i - r * NCH;
    int gy = r - 6;
    bf16x8 v = {0,0,0,0,0,0,0,0};
    if ((unsigned)gy < (unsigned)WIDTH && ch >= 1 && ch <= 7)
      v = *((const bf16x8*)(stash + plane_u + gy * WIDTH + (ch - 1) * 8));
    *((bf16x8*)&tile[r * TSTRIDE + ch * 8]) = v;
  }

  // ---- stage Toeplitz Bt ----
  if (btg) {
    const unsigned short* g = btg + (size_t)c * BT_U;
    #pragma unroll
    for (int i = 0; i < 4; ++i) {
      int ch = i * 4 + wid;
      if (ch < 13) {
        __builtin_amdgcn_global_load_lds(
            (const __attribute__((address_space(1))) unsigned int*)(g + ch * 512 + lane * 8),
            (__attribute__((address_space(3))) unsigned int*)(&Bt[ch * 512]),
            16, 0, 0);
      }
    }
  } else {
    for (int i = tid; i < 13 * 512; i += 256) {
      int ky = i >> 9, rem = i & 511, n = rem >> 5, k = rem & 31;
      int kx = k - n - 2;
      float wv = ((unsigned)kx < 13u) ? dwkw[c * 169 + ky * 13 + kx] : 0.f;
      Bt[i] = f2bf(wv);
    }
  }

  const float sk = dkg[c] * rsqrtf(dkv[c] + EPS);
  const float tk = dkb[c] - dkm[c] * sk;
  const float s1 = d1g[c] * rsqrtf(d1v[c] + EPS);
  const float a1 = d1w[c] * s1;
  const float t1 = d1b[c] - d1m[c] * s1;
  const float tsum = tk + t1;

  __syncthreads();

  const int l15  = lane & 15;   // A: m index / D: col (x offset)
  const int q    = lane >> 4;   // A/B: k quad / D: row group

  // hoist B fragments (channel-constant) into registers
  bf16x8 bfr[13];
  #pragma unroll
  for (int ky = 0; ky < 13; ++ky)
    bfr[ky] = *((const bf16x8*)&Bt[(ky * 16 + l15) * 32 + q * 8]);

  // 16 output tiles of 16x16 cover 64x64 >= 56x56; 4 waves -> 4 tiles each
  for (int t = wid; t < 16; t += 4) {
    const int y0 = (t >> 2) * 16, x0 = (t & 3) * 16;
    f32x4 acc = {0.f, 0.f, 0.f, 0.f};
    #pragma unroll
    for (int ky = 0; ky < 13; ++ky) {
      bf16x8 a = *((const bf16x8*)&tile[(y0 + l15 + ky) * TSTRIDE + x0 + q * 8]);
      acc = __builtin_amdgcn_mfma_f32_16x16x32_bf16(a, bfr[ky], acc, 0, 0, 0);
    }
    // epilogue: D row m = q*4+r, col n = l15
    const int x = x0 + l15;
    if (x < WIDTH) {
      #pragma unroll
      for (int r = 0; r < 4; ++r) {
        const int y = y0 + q * 4 + r;
        if (y < WIDTH) {
          float ctr = bf2f(tile[(y + 6) * TSTRIDE + x + 8]);
          float v = acc[r] * sk + tsum + ctr * a1;
          outf[plane_f + y * WIDTH + x] =
              0.5f * v * (1.f + erff(v * 0.70710678118654752f));
        }
      }
    }
  }
}

extern "C" void kernel_launch(void* const* d_in, const int* in_sizes, int n_in,
                              void* d_out, int out_size, void* d_ws, size_t ws_size,
                              hipStream_t stream) {
  const float* x     = (const float*)d_in[0];
  const float* pw_w  = (const float*)d_in[1];
  const float* pw_g  = (const float*)d_in[2];
  const float* pw_b  = (const float*)d_in[3];
  const float* pw_m  = (const float*)d_in[4];
  const float* pw_v  = (const float*)d_in[5];
  const float* dwk_w = (const float*)d_in[6];
  const float* dwk_g = (const float*)d_in[7];
  const float* dwk_b = (const float*)d_in[8];
  const float* dwk_m = (const float*)d_in[9];
  const float* dwk_v = (const float*)d_in[10];
  const float* dw1_w = (const float*)d_in[11];
  const float* dw1_g = (const float*)d_in[12];
  const float* dw1_b = (const float*)d_in[13];
  const float* dw1_m = (const float*)d_in[14];
  const float* dw1_v = (const float*)d_in[15];
  float* outf = (float*)d_out;
  unsigned short* outu = (unsigned short*)d_out;
  unsigned short* wpack = (unsigned short*)d_ws;   // [0, 368640) bytes

  pack_w<<<WP_TOTAL / 256, 256, 0, stream>>>(pw_w, wpack);

  unsigned short* btg = nullptr;
  if (ws_size >= (size_t)(WP_TOTAL + BT_TOTAL) * sizeof(unsigned short)) {
    btg = wpack + WP_TOTAL;
    pack_bt<<<CC, 256, 0, stream>>>(dwk_w, btg);
  }

  dim3 gridA(HW / 64, 16);
  pw_gemm_bn_res<<<gridA, 256, 0, stream>>>(x, wpack, pw_g, pw_b, pw_m, pw_v, outu);

  dim3 gridB(16 * CC);
  dw_conv_mfma<<<gridB, 256, 0, stream>>>(outf, outu, btg, dwk_w,
      dwk_g, dwk_b, dwk_m, dwk_v, dw1_w, dw1_g, dw1_b, dw1_m, dw1_v);
}